// Round 3
// baseline (447.627 us; speedup 1.0000x reference)
//
#include <hip/hip_runtime.h>

// SOM vector-quantizer fused kernel for MI355X (gfx950).
// Outputs (flat in d_out): [0] loss scalar, [1 .. 8388608] quantized_st
// in [B,C,D,H,W] layout, [8388609 ..] one-hot encodings [N,256].
//
// N = 262144 voxels, EMB_D = 32, K = 256 (16x16 SOM grid).
//
// R5 -> R6:
//  * enc one-hot rewritten as fill + scatter. R3-R5 wrote all 268 MB of
//    one-hots from the hot kernel via per-row dword stores gated on
//    readlane/cmp — effective write BW ~1.8 TB/s vs the 6.2 TB/s the
//    harness's own dwordx4 fill proves achievable on this exact buffer.
//    Now: som_prep zero-fills the enc region with aligned float4 stores
//    (same pattern as the 6.2 TB/s fill; ~48 us), and som_main stores
//    exactly one dword (the 1.0f at [n*256+bidx]) per voxel. Bytes are
//    identical; efficiency and dependency structure are not.
//  * som_main loses the whole 64-iter enc loop (256 stores + ~1000 VALU
//    per wave) -> shorter tail, fewer live regs.
//  * Scan (AS4 s_load delivery), LDS gathers, slot atomics, and the exact
//    sequential fmaf order (absmax 0.0) are untouched from R5.

#define SOM_K      256
#define EMB_D      32
#define WPAD       36             // LDS row stride (floats): 16B-aligned rows
#define N_VOX      262144
#define SPATIAL    32768          // 32*32*32 per batch
#define OUT_ELEMS  8388608        // 8*32*32768
#define ENC_ELEMS  67108864      // N_VOX * SOM_K
#define COMMIT_DEN 8388608.0f
#define NSLOT      256            // loss accumulator slots (64B apart)

#define CONST_AS __attribute__((address_space(4)))

// ---------------------------------------------------------------------------
// prep: zero the loss slots AND the 268 MB enc one-hot region.
// enc base is d_out float index 8388609 (byte offset % 16 == 4), so
// enc+3 is 16B-aligned: 3 lead dwords + 16777215 float4 + 1 tail dword.
// Grid: 2048 blocks x 256 threads, 32 float4 per thread, coalesced sweep.
// ---------------------------------------------------------------------------
__global__ __launch_bounds__(256) void som_prep_kernel(
    float* __restrict__ ws, float* __restrict__ enc) {
  const int t = threadIdx.x;
  const long tid = (long)blockIdx.x * 256 + t;     // 0 .. 524287

  if (blockIdx.x == 2047) {                        // zero the 256 loss slots
    float4* p = (float4*)ws;                       // 1024 float4
#pragma unroll
    for (int i = 0; i < 4; ++i) p[i * 256 + t] = make_float4(0.f, 0.f, 0.f, 0.f);
  }

  float4* body = (float4*)(enc + 3);               // aligned: 16777215 float4
  const float4 z4 = make_float4(0.f, 0.f, 0.f, 0.f);
#pragma unroll
  for (int i = 0; i < 32; ++i) {
    long idx = (long)i * 524288 + tid;             // coalesced full sweep
    if (idx < 16777215L) body[idx] = z4;           // exactly 1 lane skipped
  }
  if (tid == 0) {                                  // lead 3 + tail 1 dwords
    enc[0] = 0.f; enc[1] = 0.f; enc[2] = 0.f;
    enc[ENC_ELEMS - 1] = 0.f;
  }
}

// ---------------------------------------------------------------------------
// main fused kernel: 1024 blocks x 256 threads, one thread per voxel.
// ---------------------------------------------------------------------------
__global__ __launch_bounds__(256) void som_main_kernel(
    const float* __restrict__ x,     // [8,32,32,32,32]
    const float* __restrict__ w,     // [256,32]
    float* __restrict__ slots,       // ws: NSLOT x 16 floats
    float* __restrict__ out,         // d_out+1, [8,32,32768]
    float* __restrict__ enc) {       // d_out+1+OUT_ELEMS, [N,256] (pre-zeroed)
  __shared__ __align__(16) float wl[SOM_K * WPAD];
  __shared__ float wsql[SOM_K];      // ||W_k||^2

  const int t = threadIdx.x;
  // Constant-address-space view of the codebook: s_load + no-alias by
  // construction (CK cast_pointer_to_constant_address_space idiom).
  const CONST_AS float* wcp = (const CONST_AS float*)(unsigned long long)w;

  // Issue the voxel loads FIRST so they overlap the LDS staging below.
  const int n    = blockIdx.x * 256 + t;
  const int base = (n >> 15) * (EMB_D * SPATIAL) + (n & (SPATIAL - 1));
  float xv[EMB_D];
#pragma unroll
  for (int c = 0; c < EMB_D; ++c) xv[c] = x[base + c * SPATIAL];

  // Stage W -> LDS (coalesced read, padded scatter write). Needed only for
  // the divergent gather phases after the scan.
#pragma unroll
  for (int i = 0; i < 32; ++i) {
    int e = i * 256 + t;             // 0..8191
    int r = e >> 5, c = e & 31;
    wl[r * WPAD + c] = w[e];
  }
  // ||W_t||^2, same sequential-fmaf order as the reference-matched R1..R5.
  {
    float s = 0.0f;
#pragma unroll
    for (int c = 0; c < EMB_D; ++c) {
      float v = w[t * EMB_D + c];
      s = fmaf(v, v, s);
    }
    wsql[t] = s;
  }
  __syncthreads();

  float xsq = 0.0f;
#pragma unroll
  for (int c = 0; c < EMB_D; ++c) xsq = fmaf(xv[c], xv[c], xsq);

  // Distance scan over all 256 codebook rows. k is wave-uniform and wcp is
  // constant-AS -> rows arrive as s_load into SGPRs; each fmaf is
  // v_fmac_f32 vdst, sgpr, vgpr. Exact sequential fmaf order kept
  // (absmax 0.0).
  float best = 3.402823466e38f;
  int   bidx = 0;
#pragma unroll 2
  for (int k = 0; k < SOM_K; ++k) {
    const CONST_AS float* wr = wcp + (k << 5);
    float dot = 0.0f;
#pragma unroll
    for (int j = 0; j < EMB_D; ++j) dot = fmaf(wr[j], xv[j], dot);
    float d = (xsq + wsql[k]) - 2.0f * dot;   // same rounding order as ref
    if (d < best) { best = d; bidx = k; }
  }

  // One-hot: region is pre-zeroed by som_prep, write only the single 1.0.
  enc[(size_t)n * SOM_K + bidx] = 1.0f;

  // Quantized output + commitment-loss partial (gather row bidx from LDS).
  float commit = 0.0f;
  {
    const float4* qrow = (const float4*)(wl + bidx * WPAD);
#pragma unroll
    for (int j = 0; j < 8; ++j) {
      float4 q = qrow[j];
      float qq[4] = { q.x, q.y, q.z, q.w };
#pragma unroll
      for (int u = 0; u < 4; ++u) {
        int c = 4 * j + u;
        out[base + c * SPATIAL] = qq[u];     // coalesced dword store
        float df = qq[u] - xv[c];
        commit = fmaf(df, df, commit);
      }
    }
  }

  // SOM loss: dist to BMU + its up/down/left/right grid neighbors.
  float som = best;
  float cnt = 1.0f;
  {
    const int h   = bidx >> 4;
    const int wc2 = bidx & 15;
    const int   cand[4]  = { bidx - 16, bidx + 16, bidx - 1, bidx + 1 };
    const float valid[4] = { h > 0 ? 1.f : 0.f,  h < 15 ? 1.f : 0.f,
                             wc2 > 0 ? 1.f : 0.f, wc2 < 15 ? 1.f : 0.f };
#pragma unroll
    for (int j = 0; j < 4; ++j) {
      int nk = valid[j] != 0.0f ? cand[j] : bidx;   // clamp (masked anyway)
      const float4* nrow = (const float4*)(wl + nk * WPAD);
      float dot = 0.0f;
#pragma unroll
      for (int jj = 0; jj < 8; ++jj) {
        float4 q = nrow[jj];
        dot = fmaf(q.x, xv[4 * jj + 0], dot);
        dot = fmaf(q.y, xv[4 * jj + 1], dot);
        dot = fmaf(q.z, xv[4 * jj + 2], dot);
        dot = fmaf(q.w, xv[4 * jj + 3], dot);
      }
      float d = (xsq + wsql[nk]) - 2.0f * dot;
      som = fmaf(valid[j], d, som);
      cnt += valid[j];
    }
  }

  // Wave reduction -> 3 atomics per wave into this block's slot (slots are
  // 64B apart; 16 waves/slot -> negligible contention, parallel L2 banks).
  for (int off = 32; off > 0; off >>= 1) {
    commit += __shfl_down(commit, off, 64);
    som    += __shfl_down(som,    off, 64);
    cnt    += __shfl_down(cnt,    off, 64);
  }
  if ((t & 63) == 0) {
    float* sp = slots + (size_t)(blockIdx.x & (NSLOT - 1)) * 16;
    atomicAdd(sp + 0, commit);
    atomicAdd(sp + 1, som);
    atomicAdd(sp + 2, cnt);
  }
}

// ---------------------------------------------------------------------------
// final: reduce the 256 slots with one wave, then
// loss = ALPHA * mean(commit) + BETA * som_sum / total_neighbors
// ---------------------------------------------------------------------------
__global__ __launch_bounds__(64) void som_final_kernel(
    const float* __restrict__ slots, float* __restrict__ loss) {
  const int t = threadIdx.x;           // one wave
  float commit = 0.f, som = 0.f, cnt = 0.f;
#pragma unroll
  for (int i = 0; i < 4; ++i) {
    const float* sp = slots + (size_t)(i * 64 + t) * 16;
    commit += sp[0]; som += sp[1]; cnt += sp[2];
  }
  for (int off = 32; off > 0; off >>= 1) {
    commit += __shfl_down(commit, off, 64);
    som    += __shfl_down(som,    off, 64);
    cnt    += __shfl_down(cnt,    off, 64);
  }
  if (t == 0) loss[0] = 6.0f * (commit / COMMIT_DEN) + som / cnt;
}

extern "C" void kernel_launch(void* const* d_in, const int* in_sizes, int n_in,
                              void* d_out, int out_size, void* d_ws, size_t ws_size,
                              hipStream_t stream) {
  const float* x = (const float*)d_in[0];   // [8,32,32,32,32]
  const float* w = (const float*)d_in[1];   // [256,32]
  float* ws  = (float*)d_ws;                // NSLOT x 16 float slots
  float* o   = (float*)d_out;               // [0] loss, then out, then enc

  som_prep_kernel<<<2048, 256, 0, stream>>>(ws, o + 1 + OUT_ELEMS);
  som_main_kernel<<<N_VOX / 256, 256, 0, stream>>>(
      x, w, ws, o + 1, o + 1 + OUT_ELEMS);
  som_final_kernel<<<1, 64, 0, stream>>>(ws, o);
}

// Round 4
// 384.019 us; speedup vs baseline: 1.1656x; 1.1656x over previous
//
#include <hip/hip_runtime.h>

// SOM vector-quantizer fused kernel for MI355X (gfx950).
// Outputs (flat in d_out): [0] loss scalar, [1 .. 8388608] quantized_st
// in [B,C,D,H,W] layout, [8388609 ..] one-hot encodings [N,256].
//
// N = 262144 voxels, EMB_D = 32, K = 256 (16x16 SOM grid).
//
// R6 -> R7:
//  * REVERT R6's fill+scatter (serial 268 MB prep cost ~50us > the ~35us
//    it saved in main; clock-normalized ablation). enc one-hots are
//    written from main again, overlapped with the gather phases.
//  * wsql is now computed from the LDS-staged codebook (bit-identical
//    sequential fmaf, same floats) instead of per-thread global reads.
//    The old pattern w[t*32+c] made every wave load touch 64 distinct
//    cache lines (128B lane stride) -> ~512 worst-case VMEM insts/CU,
//    ~14us. LDS b128 reads with mild bank aliasing cost ~0.
//  * enc one-hot: one dwordx4 store per row per lane (cols 4L..4L+3)
//    instead of 4 dword stores -- same addresses/values, 4x fewer VMEM
//    issue slots. aligned(4) ext-vector since enc base is only 4B-aligned.
//  * __launch_bounds__(256,4) pins VGPR<=128 so all 4 blocks/CU are
//    resident (grid = exactly 4 blocks/CU); guards against an occupancy
//    cliff we cannot see in the top-5 counters.
//  * Scan (AS4 s_load delivery) and all arithmetic orders untouched.

#define SOM_K      256
#define EMB_D      32
#define WPAD       36             // LDS row stride (floats): 16B-aligned rows
#define N_VOX      262144
#define SPATIAL    32768          // 32*32*32 per batch
#define OUT_ELEMS  8388608        // 8*32*32768
#define COMMIT_DEN 8388608.0f
#define NSLOT      256            // loss accumulator slots (64B apart)

#define CONST_AS __attribute__((address_space(4)))

typedef float v4a __attribute__((ext_vector_type(4), aligned(4)));

// ---------------------------------------------------------------------------
// prep: zero the slot accumulators (ws is poisoned to 0xAA every launch).
// Layout: ws[slot*16 + {0,1,2}] = {commit, som, count} partials.
// ---------------------------------------------------------------------------
__global__ __launch_bounds__(256) void som_prep_kernel(float* __restrict__ ws) {
  float4* p = (float4*)ws;               // 256 slots * 16 floats = 1024 float4
  int t = threadIdx.x;
#pragma unroll
  for (int i = 0; i < 4; ++i) p[i * 256 + t] = make_float4(0.f, 0.f, 0.f, 0.f);
}

// ---------------------------------------------------------------------------
// main fused kernel: 1024 blocks x 256 threads, one thread per voxel.
// ---------------------------------------------------------------------------
__global__ __launch_bounds__(256, 4) void som_main_kernel(
    const float* __restrict__ x,     // [8,32,32,32,32]
    const float* __restrict__ w,     // [256,32]
    float* __restrict__ slots,       // ws: NSLOT x 16 floats
    float* __restrict__ out,         // d_out+1, [8,32,32768]
    float* __restrict__ enc) {       // d_out+1+OUT_ELEMS, [N,256]
  __shared__ __align__(16) float wl[SOM_K * WPAD];
  __shared__ float wsql[SOM_K];      // ||W_k||^2

  const int t = threadIdx.x;
  // Constant-address-space view of the codebook: s_load + no-alias by
  // construction (CK cast_pointer_to_constant_address_space idiom).
  const CONST_AS float* wcp = (const CONST_AS float*)(unsigned long long)w;

  // Issue the voxel loads FIRST so they overlap the LDS staging below.
  const int n    = blockIdx.x * 256 + t;
  const int base = (n >> 15) * (EMB_D * SPATIAL) + (n & (SPATIAL - 1));
  float xv[EMB_D];
#pragma unroll
  for (int c = 0; c < EMB_D; ++c) xv[c] = x[base + c * SPATIAL];

  // Stage W -> LDS (coalesced read, padded scatter write).
#pragma unroll
  for (int i = 0; i < 32; ++i) {
    int e = i * 256 + t;             // 0..8191
    int r = e >> 5, c = e & 31;
    wl[r * WPAD + c] = w[e];
  }
  __syncthreads();

  // ||W_t||^2 from the LDS copy -- SAME floats, SAME sequential fmaf order
  // c=0..31 as R1..R6 (bit-identical), but no uncoalesced global reads.
  {
    const float4* row = (const float4*)(wl + t * WPAD);
    float s = 0.0f;
#pragma unroll
    for (int j = 0; j < 8; ++j) {
      float4 q = row[j];
      s = fmaf(q.x, q.x, s);
      s = fmaf(q.y, q.y, s);
      s = fmaf(q.z, q.z, s);
      s = fmaf(q.w, q.w, s);
    }
    wsql[t] = s;
  }

  float xsq = 0.0f;
#pragma unroll
  for (int c = 0; c < EMB_D; ++c) xsq = fmaf(xv[c], xv[c], xsq);
  __syncthreads();

  // Distance scan over all 256 codebook rows. k is wave-uniform and wcp is
  // constant-AS -> rows arrive as s_load into SGPRs; each fmaf is
  // v_fmac_f32 vdst, sgpr, vgpr. Exact sequential fmaf order kept
  // (absmax 0.0).
  float best = 3.402823466e38f;
  int   bidx = 0;
#pragma unroll 2
  for (int k = 0; k < SOM_K; ++k) {
    const CONST_AS float* wr = wcp + (k << 5);
    float dot = 0.0f;
#pragma unroll
    for (int j = 0; j < EMB_D; ++j) dot = fmaf(wr[j], xv[j], dot);
    float d = (xsq + wsql[k]) - 2.0f * dot;   // same rounding order as ref
    if (d < best) { best = d; bidx = k; }
  }

  // One-hot encodings FIRST (only needs bidx): start draining the 268 MB
  // write stream while the LDS gather phases below run. Each wave broadcasts
  // its own 64 BMU indices via v_readlane; lane L covers columns 4L..4L+3
  // of each row -> ONE dwordx4 store per row per lane, 1KB coalesced/inst.
  // (enc base is 4B-aligned only -> aligned(4) vector store; gfx950
  // supports unaligned global vector access.)
  {
    const int lane = t & 63, wave = t >> 6;
    const int c0 = lane * 4;
    float* ep = enc + (size_t)(blockIdx.x * 256 + wave * 64) * SOM_K + c0;
    for (int row = 0; row < 64; ++row) {
      const int src = __builtin_amdgcn_readlane(bidx, row);  // wave-uniform
      v4a v;
      v.x = (c0     == src) ? 1.0f : 0.0f;
      v.y = (c0 + 1 == src) ? 1.0f : 0.0f;
      v.z = (c0 + 2 == src) ? 1.0f : 0.0f;
      v.w = (c0 + 3 == src) ? 1.0f : 0.0f;
      *(v4a*)ep = v;
      ep += SOM_K;
    }
  }

  // Quantized output + commitment-loss partial (gather row bidx from LDS).
  float commit = 0.0f;
  {
    const float4* qrow = (const float4*)(wl + bidx * WPAD);
#pragma unroll
    for (int j = 0; j < 8; ++j) {
      float4 q = qrow[j];
      float qq[4] = { q.x, q.y, q.z, q.w };
#pragma unroll
      for (int u = 0; u < 4; ++u) {
        int c = 4 * j + u;
        out[base + c * SPATIAL] = qq[u];     // coalesced dword store
        float df = qq[u] - xv[c];
        commit = fmaf(df, df, commit);
      }
    }
  }

  // SOM loss: dist to BMU + its up/down/left/right grid neighbors.
  float som = best;
  float cnt = 1.0f;
  {
    const int h   = bidx >> 4;
    const int wc2 = bidx & 15;
    const int   cand[4]  = { bidx - 16, bidx + 16, bidx - 1, bidx + 1 };
    const float valid[4] = { h > 0 ? 1.f : 0.f,  h < 15 ? 1.f : 0.f,
                             wc2 > 0 ? 1.f : 0.f, wc2 < 15 ? 1.f : 0.f };
#pragma unroll
    for (int j = 0; j < 4; ++j) {
      int nk = valid[j] != 0.0f ? cand[j] : bidx;   // clamp (masked anyway)
      const float4* nrow = (const float4*)(wl + nk * WPAD);
      float dot = 0.0f;
#pragma unroll
      for (int jj = 0; jj < 8; ++jj) {
        float4 q = nrow[jj];
        dot = fmaf(q.x, xv[4 * jj + 0], dot);
        dot = fmaf(q.y, xv[4 * jj + 1], dot);
        dot = fmaf(q.z, xv[4 * jj + 2], dot);
        dot = fmaf(q.w, xv[4 * jj + 3], dot);
      }
      float d = (xsq + wsql[nk]) - 2.0f * dot;
      som = fmaf(valid[j], d, som);
      cnt += valid[j];
    }
  }

  // Wave reduction -> 3 atomics per wave into this block's slot (slots are
  // 64B apart; 16 waves/slot -> negligible contention, parallel L2 banks).
  for (int off = 32; off > 0; off >>= 1) {
    commit += __shfl_down(commit, off, 64);
    som    += __shfl_down(som,    off, 64);
    cnt    += __shfl_down(cnt,    off, 64);
  }
  if ((t & 63) == 0) {
    float* sp = slots + (size_t)(blockIdx.x & (NSLOT - 1)) * 16;
    atomicAdd(sp + 0, commit);
    atomicAdd(sp + 1, som);
    atomicAdd(sp + 2, cnt);
  }
}

// ---------------------------------------------------------------------------
// final: reduce the 256 slots with one wave, then
// loss = ALPHA * mean(commit) + BETA * som_sum / total_neighbors
// ---------------------------------------------------------------------------
__global__ __launch_bounds__(64) void som_final_kernel(
    const float* __restrict__ slots, float* __restrict__ loss) {
  const int t = threadIdx.x;           // one wave
  float commit = 0.f, som = 0.f, cnt = 0.f;
#pragma unroll
  for (int i = 0; i < 4; ++i) {
    const float* sp = slots + (size_t)(i * 64 + t) * 16;
    commit += sp[0]; som += sp[1]; cnt += sp[2];
  }
  for (int off = 32; off > 0; off >>= 1) {
    commit += __shfl_down(commit, off, 64);
    som    += __shfl_down(som,    off, 64);
    cnt    += __shfl_down(cnt,    off, 64);
  }
  if (t == 0) loss[0] = 6.0f * (commit / COMMIT_DEN) + som / cnt;
}

extern "C" void kernel_launch(void* const* d_in, const int* in_sizes, int n_in,
                              void* d_out, int out_size, void* d_ws, size_t ws_size,
                              hipStream_t stream) {
  const float* x = (const float*)d_in[0];   // [8,32,32,32,32]
  const float* w = (const float*)d_in[1];   // [256,32]
  float* ws  = (float*)d_ws;                // NSLOT x 16 float slots
  float* o   = (float*)d_out;               // [0] loss, then out, then enc

  som_prep_kernel<<<1, 256, 0, stream>>>(ws);
  som_main_kernel<<<N_VOX / 256, 256, 0, stream>>>(
      x, w, ws, o + 1, o + 1 + OUT_ELEMS);
  som_final_kernel<<<1, 64, 0, stream>>>(ws, o);
}